// Round 1
// baseline (137.724 us; speedup 1.0000x reference)
//
#include <hip/hip_runtime.h>

#define B 4
#define TQ 256
#define TK 1024
#define QS 512
#define NN 128

// exp(2y) = exp2(y * 2*log2(e)); K1 stores E = exp2(TANH_SCALE * proj) so
// K2's tanh needs only one rcp: tanh(aq+ak) = 1 - 2/(1 + Eq*Ek).
#define TANH_SCALE 2.8853900817779268f
#define LOG2E 1.4426950408889634f
#define CTX_ELEMS ((size_t)B * TQ * QS)

typedef unsigned short ushort_t;
typedef __attribute__((ext_vector_type(8))) short bfrag;   // 8 bf16 = 4 VGPR
typedef __attribute__((ext_vector_type(4))) float ffrag;   // 4 f32 acc

union FragU { uint4 u; bfrag s; };

__device__ __forceinline__ float fast_exp2(float x) {
#if __has_builtin(__builtin_amdgcn_exp2f)
    return __builtin_amdgcn_exp2f(x);
#else
    return exp2f(x);
#endif
}
__device__ __forceinline__ float fast_rcp(float x) {
#if __has_builtin(__builtin_amdgcn_rcpf)
    return __builtin_amdgcn_rcpf(x);
#else
    return 1.0f / x;
#endif
}

// v_cvt_pk_bf16_f32: dst[15:0]=bf16(a), dst[31:16]=bf16(b)
__device__ __forceinline__ unsigned int pk_bf16(float a, float b) {
    unsigned int r;
    asm("v_cvt_pk_bf16_f32 %0, %1, %2" : "=v"(r) : "v"(a), "v"(b));
    return r;
}
__device__ __forceinline__ float lo16f(unsigned int u) { return __uint_as_float(u << 16); }
__device__ __forceinline__ float hi16f(unsigned int u) { return __uint_as_float(u & 0xffff0000u); }

// Split 8 consecutive fp32 (a0,a1) into hi/lo bf16x8 fragments (bf16x3 trick).
__device__ __forceinline__ void split_frag(float4 a0, float4 a1, FragU& hi, FragU& lo) {
    const unsigned int h0 = pk_bf16(a0.x, a0.y), h1 = pk_bf16(a0.z, a0.w);
    const unsigned int h2 = pk_bf16(a1.x, a1.y), h3 = pk_bf16(a1.z, a1.w);
    const float l0 = a0.x - lo16f(h0), l1 = a0.y - hi16f(h0);
    const float l2 = a0.z - lo16f(h1), l3 = a0.w - hi16f(h1);
    const float l4 = a1.x - lo16f(h2), l5 = a1.y - hi16f(h2);
    const float l6 = a1.z - lo16f(h3), l7 = a1.w - hi16f(h3);
    hi.u = make_uint4(h0, h1, h2, h3);
    lo.u = make_uint4(pk_bf16(l0, l1), pk_bf16(l2, l3),
                      pk_bf16(l4, l5), pk_bf16(l6, l7));
}

// ---------------------------------------------------------------------------
// K0: one-time transpose + bf16 hi/lo split of the MFMA B-operands.
//   keys  [b][1024][512] -> keysT_hi/lo [b][512][1024]  (bf16)
//   Wq,Wk [512][128]     -> WT_hi/lo    [2][128][512]   (bf16)
// 32x32 tiles through LDS (pad 33). Grid = 4*32*16 + 2*16*4 = 2176 blocks.
// ---------------------------------------------------------------------------
__global__ __launch_bounds__(256) void transpose_split_kernel(
    const float* __restrict__ keys, const float* __restrict__ Wq,
    const float* __restrict__ Wk,
    ushort_t* __restrict__ keysT_hi, ushort_t* __restrict__ keysT_lo,
    ushort_t* __restrict__ WT_hi, ushort_t* __restrict__ WT_lo)
{
    __shared__ float t[32][33];
    const int tid = threadIdx.x;
    const int bid = blockIdx.x;
    const float* src; ushort_t *dh, *dl;
    int srcLD, dstLD, r0, c0;
    if (bid < 2048) {
        const int b = bid >> 9, tt = bid & 511;
        const int kt = tt & 31, dt = tt >> 5;
        src = keys + (size_t)b * TK * QS; srcLD = QS;
        dh = keysT_hi + (size_t)b * QS * TK;
        dl = keysT_lo + (size_t)b * QS * TK;
        dstLD = TK; r0 = kt * 32; c0 = dt * 32;
    } else {
        const int tt = bid - 2048;
        const int m = tt >> 6, t2 = tt & 63;
        const int kt = t2 & 15, nt = t2 >> 4;
        src = m ? Wk : Wq; srcLD = NN;
        dh = WT_hi + (size_t)m * NN * QS;
        dl = WT_lo + (size_t)m * NN * QS;
        dstLD = QS; r0 = kt * 32; c0 = nt * 32;
    }
    {
        const int rr = tid >> 3, cc = (tid & 7) * 4;
        const float4 v = *(const float4*)(src + (size_t)(r0 + rr) * srcLD + c0 + cc);
        t[rr][cc + 0] = v.x; t[rr][cc + 1] = v.y;
        t[rr][cc + 2] = v.z; t[rr][cc + 3] = v.w;
    }
    __syncthreads();
    {
        const int dr = tid >> 3, kc = (tid & 7) * 4;
        const float v0 = t[kc + 0][dr], v1 = t[kc + 1][dr];
        const float v2 = t[kc + 2][dr], v3 = t[kc + 3][dr];
        const unsigned int h01 = pk_bf16(v0, v1), h23 = pk_bf16(v2, v3);
        const float l0 = v0 - lo16f(h01), l1 = v1 - hi16f(h01);
        const float l2 = v2 - lo16f(h23), l3 = v3 - hi16f(h23);
        const unsigned int L01 = pk_bf16(l0, l1), L23 = pk_bf16(l2, l3);
        const size_t o = (size_t)(c0 + dr) * dstLD + r0 + kc;
        uint2 h; h.x = h01; h.y = h23;
        uint2 L; L.x = L01; L.y = L23;
        *(uint2*)(dh + o) = h;
        *(uint2*)(dl + o) = L;
    }
}

// ---------------------------------------------------------------------------
// K1: fused projections via bf16x3 MFMA (16x16x32). Row space =
// [1024 q ; 4096 k]. Block = 32 rows x 128 n, 4 waves, wave tile 16x64.
// A (fp32) staged per-wave in private LDS (no __syncthreads in K-loop ->
// no vmcnt(0) barrier drain; B loads pipeline across iterations).
// B-fragments load directly from pre-split WT[n][k] planes (L2-resident).
// Epilogue stores E = exp2(TANH_SCALE*proj): attq[row][n], attkT[b][n][k].
// ---------------------------------------------------------------------------
__global__ __launch_bounds__(256) void proj_mfma_kernel(
    const float* __restrict__ query, const float* __restrict__ keys,
    const ushort_t* __restrict__ WT_hi, const ushort_t* __restrict__ WT_lo,
    float* __restrict__ attq, float* __restrict__ attkT)
{
    __shared__ float As[4][16][36];   // per-wave private, pad 36 (b128-aligned)
    const int tid = threadIdx.x, lane = tid & 63, w = tid >> 6;
    const int r0 = blockIdx.x * 32;
    const bool isq = (r0 < B * TQ);
    const float* Abase = isq ? (query + (size_t)r0 * QS)
                             : (keys + (size_t)(r0 - B * TQ) * QS);
    const ushort_t* BH = WT_hi + (isq ? 0 : (size_t)NN * QS);
    const ushort_t* BL = WT_lo + (isq ? 0 : (size_t)NN * QS);
    const int rb = w >> 1;            // which 16-row sub-block
    const int nb0 = (w & 1) * 64;     // which n half
    const int frow = lane & 15, fg = lane >> 4;
    const float* Arow = Abase + (size_t)(rb * 16) * QS;

    ffrag acc[4] = {};
    #pragma unroll 2
    for (int kb = 0; kb < QS; kb += 32) {
        FragU bh[4], bl[4];
        #pragma unroll
        for (int nb = 0; nb < 4; ++nb) {
            const size_t off = (size_t)(nb0 + nb * 16 + frow) * QS + kb + fg * 8;
            bh[nb].u = *(const uint4*)(BH + off);
            bl[nb].u = *(const uint4*)(BL + off);
        }
        #pragma unroll
        for (int it = 0; it < 2; ++it) {
            const int f = lane + it * 64;
            const int rr = f >> 3, cc = f & 7;
            *(float4*)&As[w][rr][cc * 4] =
                *(const float4*)(Arow + (size_t)rr * QS + kb + cc * 4);
        }
        // same-wave DS ops are in-order; per-thread may-alias keeps compiler
        // from reordering the frag reads above the staging writes.
        const float4 a0 = *(const float4*)&As[w][frow][fg * 8];
        const float4 a1 = *(const float4*)&As[w][frow][fg * 8 + 4];
        FragU ah, al;
        split_frag(a0, a1, ah, al);
        #pragma unroll
        for (int nb = 0; nb < 4; ++nb) {
            acc[nb] = __builtin_amdgcn_mfma_f32_16x16x32_bf16(al.s, bh[nb].s, acc[nb], 0, 0, 0);
            acc[nb] = __builtin_amdgcn_mfma_f32_16x16x32_bf16(ah.s, bl[nb].s, acc[nb], 0, 0, 0);
            acc[nb] = __builtin_amdgcn_mfma_f32_16x16x32_bf16(ah.s, bh[nb].s, acc[nb], 0, 0, 0);
        }
    }

    const int orow = rb * 16 + fg * 4;  // D row = 4*(l>>4)+r within sub-block
    if (isq) {
        #pragma unroll
        for (int nb = 0; nb < 4; ++nb) {
            const int n = nb0 + nb * 16 + frow;
            #pragma unroll
            for (int r = 0; r < 4; ++r)
                attq[(size_t)(r0 + orow + r) * NN + n] =
                    fast_exp2(acc[nb][r] * TANH_SCALE);
        }
    } else {
        const int rk = r0 - B * TQ;
        const int bb = rk >> 10;
        const int kk = (rk & 1023) + orow;   // 4 consecutive k per lane
        #pragma unroll
        for (int nb = 0; nb < 4; ++nb) {
            const int n = nb0 + nb * 16 + frow;
            float4 o;
            o.x = fast_exp2(acc[nb][0] * TANH_SCALE);
            o.y = fast_exp2(acc[nb][1] * TANH_SCALE);
            o.z = fast_exp2(acc[nb][2] * TANH_SCALE);
            o.w = fast_exp2(acc[nb][3] * TANH_SCALE);
            *(float4*)(attkT + (size_t)bb * NN * TK + (size_t)n * TK + kk) = o;
        }
    }
}

// ---------------------------------------------------------------------------
// K2: scores + softmax via the 1-rcp tanh. Unchanged (rcp-throughput bound).
// ---------------------------------------------------------------------------
__global__ __launch_bounds__(256) void score_softmax_kernel(
    const float* __restrict__ attq, const float* __restrict__ attkT,
    const float* __restrict__ vatt, float* __restrict__ wout)
{
    __shared__ float eqs[2][128];
    __shared__ float nv2[128];     // -2 * vatt
    __shared__ float red[2][8];

    const int tid = threadIdx.x;
    const int b = blockIdx.x >> 7;
    const int q0 = (blockIdx.x & 127) * 2;

    if (tid < 128) {
        eqs[0][tid] = attq[((size_t)b * TQ + q0) * NN + tid];
        nv2[tid] = -2.0f * vatt[tid];
    } else {
        eqs[1][tid & 127] = attq[((size_t)b * TQ + q0 + 1) * NN + (tid & 127)];
    }
    __syncthreads();

    const float* kt = attkT + (size_t)b * NN * TK + (size_t)tid * 4;
    float s[2][4] = {};

    #pragma unroll 8
    for (int n = 0; n < 128; ++n) {
        const float4 a = *(const float4*)(kt + (size_t)n * TK);
        const float e0 = eqs[0][n], e1 = eqs[1][n], nv = nv2[n];
        const float av[4] = {a.x, a.y, a.z, a.w};
        #pragma unroll
        for (int rr = 0; rr < 4; ++rr) {
            const float r0 = fast_rcp(fmaf(av[rr], e0, 1.0f));
            s[0][rr] = fmaf(nv, r0, s[0][rr]);
            const float r1 = fast_rcp(fmaf(av[rr], e1, 1.0f));
            s[1][rr] = fmaf(nv, r1, s[1][rr]);
        }
    }

    const int lane = tid & 63, wid = tid >> 6;
    #pragma unroll
    for (int qq = 0; qq < 2; ++qq) {
        float mm = fmaxf(fmaxf(s[qq][0], s[qq][1]), fmaxf(s[qq][2], s[qq][3]));
        #pragma unroll
        for (int off = 32; off > 0; off >>= 1)
            mm = fmaxf(mm, __shfl_xor(mm, off, 64));
        if (lane == 0) red[qq][wid] = mm;
    }
    __syncthreads();
    float m[2];
    m[0] = fmaxf(fmaxf(red[0][0], red[0][1]), fmaxf(red[0][2], red[0][3]));
    m[1] = fmaxf(fmaxf(red[1][0], red[1][1]), fmaxf(red[1][2], red[1][3]));

    float e[2][4];
    #pragma unroll
    for (int qq = 0; qq < 2; ++qq) {
        float ls = 0.f;
        #pragma unroll
        for (int i = 0; i < 4; ++i) {
            e[qq][i] = fast_exp2((s[qq][i] - m[qq]) * LOG2E);
            ls += e[qq][i];
        }
        #pragma unroll
        for (int off = 32; off > 0; off >>= 1)
            ls += __shfl_xor(ls, off, 64);
        if (lane == 0) red[qq][4 + wid] = ls;
    }
    __syncthreads();
    #pragma unroll
    for (int qq = 0; qq < 2; ++qq) {
        const float S = red[qq][4] + red[qq][5] + red[qq][6] + red[qq][7];
        const float inv = fast_rcp(S);
        float4 w4;
        w4.x = e[qq][0] * inv; w4.y = e[qq][1] * inv;
        w4.z = e[qq][2] * inv; w4.w = e[qq][3] * inv;
        *(float4*)(wout + ((size_t)b * TQ + q0 + qq) * TK + (size_t)tid * 4) = w4;
    }
}

// ---------------------------------------------------------------------------
// K3: context partials via bf16x3 MFMA. Block = 32q x 128d, split-K=4.
// Grid = 4b * 8qt * 4dt * 4ks = 512 blocks (2/CU). A = wts (fp32, staged
// per-wave, split at read); B = keysT hi/lo planes direct from L2.
// Writes the same ctxp[ks][b][q][d] layout K4 expects.
// ---------------------------------------------------------------------------
__global__ __launch_bounds__(256) void context_mfma_kernel(
    const float* __restrict__ wts, const ushort_t* __restrict__ KTh,
    const ushort_t* __restrict__ KTl, float* __restrict__ ctxp)
{
    __shared__ float As[4][16][36];
    const int tid = threadIdx.x, lane = tid & 63, w = tid >> 6;
    const int bid = blockIdx.x;
    const int ks = bid & 3, dt = (bid >> 2) & 3;
    const int qt = (bid >> 4) & 7, b = bid >> 7;
    const int rb = w >> 1, nb0 = (w & 1) * 64;
    const int frow = lane & 15, fg = lane >> 4;

    const float* Arow = wts + ((size_t)b * TQ + qt * 32 + rb * 16) * TK + ks * 256;
    const ushort_t* BH = KTh + ((size_t)b * QS + dt * 128) * TK + ks * 256;
    const ushort_t* BL = KTl + ((size_t)b * QS + dt * 128) * TK + ks * 256;

    ffrag acc[4] = {};
    #pragma unroll 2
    for (int kb = 0; kb < 256; kb += 32) {
        FragU bh[4], bl[4];
        #pragma unroll
        for (int nb = 0; nb < 4; ++nb) {
            const size_t off = (size_t)(nb0 + nb * 16 + frow) * TK + kb + fg * 8;
            bh[nb].u = *(const uint4*)(BH + off);
            bl[nb].u = *(const uint4*)(BL + off);
        }
        #pragma unroll
        for (int it = 0; it < 2; ++it) {
            const int f = lane + it * 64, rr = f >> 3, cc = f & 7;
            *(float4*)&As[w][rr][cc * 4] =
                *(const float4*)(Arow + (size_t)rr * TK + kb + cc * 4);
        }
        const float4 a0 = *(const float4*)&As[w][frow][fg * 8];
        const float4 a1 = *(const float4*)&As[w][frow][fg * 8 + 4];
        FragU ah, al;
        split_frag(a0, a1, ah, al);
        #pragma unroll
        for (int nb = 0; nb < 4; ++nb) {
            acc[nb] = __builtin_amdgcn_mfma_f32_16x16x32_bf16(al.s, bh[nb].s, acc[nb], 0, 0, 0);
            acc[nb] = __builtin_amdgcn_mfma_f32_16x16x32_bf16(ah.s, bl[nb].s, acc[nb], 0, 0, 0);
            acc[nb] = __builtin_amdgcn_mfma_f32_16x16x32_bf16(ah.s, bh[nb].s, acc[nb], 0, 0, 0);
        }
    }

    const int qrow = qt * 32 + rb * 16 + fg * 4;
    float* op = ctxp + (size_t)ks * CTX_ELEMS
              + ((size_t)b * TQ + qrow) * QS + dt * 128 + nb0 + frow;
    #pragma unroll
    for (int nb = 0; nb < 4; ++nb) {
        #pragma unroll
        for (int r = 0; r < 4; ++r)
            op[(size_t)r * QS + nb * 16] = acc[nb][r];
    }
}

// ---------------------------------------------------------------------------
// K4: reduce the 4 split-K partials into ctx. 131072 float4 outputs.
// ---------------------------------------------------------------------------
__global__ __launch_bounds__(256) void reduce_kernel(
    const float4* __restrict__ ctxp, float4* __restrict__ ctx)
{
    const size_t idx = (size_t)blockIdx.x * 256 + threadIdx.x;
    const size_t stride = CTX_ELEMS / 4;
    const float4 a = ctxp[idx];
    const float4 b = ctxp[idx + stride];
    const float4 c = ctxp[idx + 2 * stride];
    const float4 d = ctxp[idx + 3 * stride];
    float4 o;
    o.x = (a.x + b.x) + (c.x + d.x);
    o.y = (a.y + b.y) + (c.y + d.y);
    o.z = (a.z + b.z) + (c.z + d.z);
    o.w = (a.w + b.w) + (c.w + d.w);
    ctx[idx] = o;
}

// ---------------------------------------------------------------------------
extern "C" void kernel_launch(void* const* d_in, const int* in_sizes, int n_in,
                              void* d_out, int out_size, void* d_ws, size_t ws_size,
                              hipStream_t stream) {
    const float* query = (const float*)d_in[0];  // (4,256,512)
    const float* keys  = (const float*)d_in[1];  // (4,1024,512)
    const float* Wq    = (const float*)d_in[2];  // (512,128)
    const float* Wk    = (const float*)d_in[3];  // (512,128)
    const float* vatt  = (const float*)d_in[4];  // (128,)

    float* ctx = (float*)d_out;                  // 4*256*512
    float* wts = ctx + CTX_ELEMS;                // 4*256*1024

    float* attq  = (float*)d_ws;                        // 4*256*128   (E-values)
    float* attkT = attq + (size_t)B * TQ * NN;          // 4*128*1024  (E, transposed)
    float* ctxp  = attkT + (size_t)B * NN * TK;         // 4 * CTX_ELEMS partials
    ushort_t* keysT_hi = (ushort_t*)(ctxp + 4 * CTX_ELEMS);      // [4][512][1024] bf16
    ushort_t* keysT_lo = keysT_hi + (size_t)B * QS * TK;
    ushort_t* WT_hi    = keysT_lo + (size_t)B * QS * TK;         // [2][128][512] bf16
    ushort_t* WT_lo    = WT_hi + (size_t)2 * NN * QS;

    hipLaunchKernelGGL(transpose_split_kernel, dim3(2176), dim3(256), 0, stream,
                       keys, Wq, Wk, keysT_hi, keysT_lo, WT_hi, WT_lo);
    hipLaunchKernelGGL(proj_mfma_kernel, dim3(160), dim3(256), 0, stream,
                       query, keys, WT_hi, WT_lo, attq, attkT);
    hipLaunchKernelGGL(score_softmax_kernel, dim3(B * TQ / 2), dim3(256), 0,
                       stream, attq, attkT, vatt, wts);
    hipLaunchKernelGGL(context_mfma_kernel, dim3(512), dim3(256), 0, stream,
                       wts, keysT_hi, keysT_lo, ctxp);
    hipLaunchKernelGGL(reduce_kernel, dim3((unsigned)(CTX_ELEMS / 4 / 256)), dim3(256), 0,
                       stream, (const float4*)ctxp, (float4*)ctx);
}